// Round 2
// baseline (1633.891 us; speedup 1.0000x reference)
//
#include <hip/hip_runtime.h>

#define N_NODES 100000
#define N_EDGES 3200000
#define F_IN 256
#define H1 64
#define H2 32
#define C_OUT 1000

// ---------------- init / degree ----------------
__global__ void k_init(float* __restrict__ deg, float* __restrict__ g) {
    int i = blockIdx.x * 256 + threadIdx.x;
    if (i < N_NODES) deg[i] = 1.0f;  // self-loop
    if (blockIdx.x == 0 && threadIdx.x < H2) g[threadIdx.x] = 0.0f;
}

__global__ void k_count(const int* __restrict__ dst, float* __restrict__ deg) {
    int e = blockIdx.x * 256 + threadIdx.x;
    if (e < N_EDGES) atomicAdd(&deg[dst[e]], 1.0f);
}

__global__ void k_rsqrt(float* __restrict__ deg) {
    int i = blockIdx.x * 256 + threadIdx.x;
    if (i < N_NODES) deg[i] = rsqrtf(deg[i]);
}

// ---------------- layer-1 GEMM: y1 = dinv * (x @ W1); acc1 = y1 ----------------
__global__ __launch_bounds__(256) void k_gemm1(const float* __restrict__ x,
                                               const float* __restrict__ W1,
                                               const float* __restrict__ dinv,
                                               float* __restrict__ y1,
                                               float* __restrict__ acc1) {
    __shared__ float w[F_IN][H1];  // 64 KB
    {
        const float4* Wv = (const float4*)W1;
        float4* wv = (float4*)&w[0][0];
        for (int i = threadIdx.x; i < F_IN * H1 / 4; i += 256) wv[i] = Wv[i];
    }
    __syncthreads();
    int n = blockIdx.x * 256 + threadIdx.x;
    if (n >= N_NODES) return;

    float acc[H1];
#pragma unroll
    for (int j = 0; j < H1; j++) acc[j] = 0.0f;

    const float4* xr = (const float4*)(x + (size_t)n * F_IN);
#pragma unroll 2
    for (int k0 = 0; k0 < F_IN / 4; k0++) {
        float4 xq = xr[k0];
#pragma unroll
        for (int d = 0; d < 4; d++) {
            float xv = (d == 0 ? xq.x : d == 1 ? xq.y : d == 2 ? xq.z : xq.w);
            const float4* wr = (const float4*)&w[k0 * 4 + d][0];
#pragma unroll
            for (int j4 = 0; j4 < H1 / 4; j4++) {
                float4 wq = wr[j4];
                acc[j4 * 4 + 0] += xv * wq.x;
                acc[j4 * 4 + 1] += xv * wq.y;
                acc[j4 * 4 + 2] += xv * wq.z;
                acc[j4 * 4 + 3] += xv * wq.w;
            }
        }
    }
    float dv = dinv[n];
    float4* y1r = (float4*)(y1 + (size_t)n * H1);
    float4* a1r = (float4*)(acc1 + (size_t)n * H1);
#pragma unroll
    for (int j4 = 0; j4 < H1 / 4; j4++) {
        float4 o;
        o.x = acc[j4 * 4 + 0] * dv;
        o.y = acc[j4 * 4 + 1] * dv;
        o.z = acc[j4 * 4 + 2] * dv;
        o.w = acc[j4 * 4 + 3] * dv;
        y1r[j4] = o;
        a1r[j4] = o;
    }
}

// ---------------- edge scatter (atomics) ----------------
__global__ __launch_bounds__(256) void k_scatter1(const int* __restrict__ src,
                                                  const int* __restrict__ dst,
                                                  const float* __restrict__ y1,
                                                  float* __restrict__ acc1) {
    unsigned tid = blockIdx.x * 256u + threadIdx.x;  // E*64 threads
    unsigned e = tid >> 6, c = tid & 63u;
    if (e < N_EDGES) {
        int s = src[e], d = dst[e];
        atomicAdd(&acc1[(size_t)d * H1 + c], y1[(size_t)s * H1 + c]);
    }
}

__global__ void k_finish1(float* __restrict__ acc1, const float* __restrict__ dinv,
                          const float* __restrict__ b1) {
    unsigned tid = blockIdx.x * 256u + threadIdx.x;  // N*64
    if (tid < (unsigned)N_NODES * H1) {
        unsigned n = tid >> 6, c = tid & 63u;
        float v = dinv[n] * acc1[tid] + b1[c];
        acc1[tid] = v > 0.0f ? v : 0.0f;  // acc1 becomes h1
    }
}

// ---------------- layer-2 GEMM: y2 = dinv * (h1 @ W2); acc2 = y2 ----------------
__global__ __launch_bounds__(256) void k_gemm2(const float* __restrict__ h1,
                                               const float* __restrict__ W2,
                                               const float* __restrict__ dinv,
                                               float* __restrict__ y2,
                                               float* __restrict__ acc2) {
    __shared__ float w[H1][H2];  // 8 KB
    {
        const float4* Wv = (const float4*)W2;
        float4* wv = (float4*)&w[0][0];
        for (int i = threadIdx.x; i < H1 * H2 / 4; i += 256) wv[i] = Wv[i];
    }
    __syncthreads();
    int n = blockIdx.x * 256 + threadIdx.x;
    if (n >= N_NODES) return;

    float acc[H2];
#pragma unroll
    for (int j = 0; j < H2; j++) acc[j] = 0.0f;

    const float4* xr = (const float4*)(h1 + (size_t)n * H1);
#pragma unroll 2
    for (int k0 = 0; k0 < H1 / 4; k0++) {
        float4 xq = xr[k0];
#pragma unroll
        for (int d = 0; d < 4; d++) {
            float xv = (d == 0 ? xq.x : d == 1 ? xq.y : d == 2 ? xq.z : xq.w);
            const float4* wr = (const float4*)&w[k0 * 4 + d][0];
#pragma unroll
            for (int j4 = 0; j4 < H2 / 4; j4++) {
                float4 wq = wr[j4];
                acc[j4 * 4 + 0] += xv * wq.x;
                acc[j4 * 4 + 1] += xv * wq.y;
                acc[j4 * 4 + 2] += xv * wq.z;
                acc[j4 * 4 + 3] += xv * wq.w;
            }
        }
    }
    float dv = dinv[n];
    float4* y2r = (float4*)(y2 + (size_t)n * H2);
    float4* a2r = (float4*)(acc2 + (size_t)n * H2);
#pragma unroll
    for (int j4 = 0; j4 < H2 / 4; j4++) {
        float4 o;
        o.x = acc[j4 * 4 + 0] * dv;
        o.y = acc[j4 * 4 + 1] * dv;
        o.z = acc[j4 * 4 + 2] * dv;
        o.w = acc[j4 * 4 + 3] * dv;
        y2r[j4] = o;
        a2r[j4] = o;
    }
}

__global__ __launch_bounds__(256) void k_scatter2(const int* __restrict__ src,
                                                  const int* __restrict__ dst,
                                                  const float* __restrict__ y2,
                                                  float* __restrict__ acc2) {
    unsigned tid = blockIdx.x * 256u + threadIdx.x;  // E*32 threads
    unsigned e = tid >> 5, c = tid & 31u;
    if (e < N_EDGES) {
        int s = src[e], d = dst[e];
        atomicAdd(&acc2[(size_t)d * H2 + c], y2[(size_t)s * H2 + c]);
    }
}

// ---------------- finish2 + mean pool (partial sums into g[32]) ----------------
__global__ __launch_bounds__(256) void k_finish2_pool(const float* __restrict__ acc2,
                                                      const float* __restrict__ dinv,
                                                      const float* __restrict__ b2,
                                                      float* __restrict__ g) {
    __shared__ float red[256];
    unsigned t = threadIdx.x;
    unsigned n = blockIdx.x * 8u + (t >> 5);
    unsigned c = t & 31u;
    float v = 0.0f;
    if (n < N_NODES) {
        float hv = dinv[n] * acc2[(size_t)n * H2 + c] + b2[c];
        v = hv > 0.0f ? hv : 0.0f;
    }
    red[t] = v;
    __syncthreads();
    if (t < 128) red[t] += red[t + 128];
    __syncthreads();
    if (t < 64) red[t] += red[t + 64];
    __syncthreads();
    if (t < 32) {
        float s = red[t] + red[t + 32];
        atomicAdd(&g[t], s);
    }
}

__global__ void k_fc(const float* __restrict__ g, const float* __restrict__ Wfc,
                     const float* __restrict__ bfc, float* __restrict__ out) {
    int c = blockIdx.x * 256 + threadIdx.x;
    if (c < C_OUT) {
        const float invn = 1.0f / (float)N_NODES;
        float s = bfc[c];
#pragma unroll
        for (int k = 0; k < H2; k++) s += (g[k] * invn) * Wfc[k * C_OUT + c];
        out[c] = s;
    }
}

extern "C" void kernel_launch(void* const* d_in, const int* in_sizes, int n_in,
                              void* d_out, int out_size, void* d_ws, size_t ws_size,
                              hipStream_t stream) {
    const float* x   = (const float*)d_in[0];
    const int* esrc  = (const int*)d_in[1];
    const int* edst  = (const int*)d_in[2];
    const float* W1  = (const float*)d_in[3];
    const float* b1  = (const float*)d_in[4];
    const float* W2  = (const float*)d_in[5];
    const float* b2  = (const float*)d_in[6];
    const float* Wfc = (const float*)d_in[7];
    const float* bfc = (const float*)d_in[8];
    float* out = (float*)d_out;

    float* ws = (float*)d_ws;
    // workspace layout (float offsets)
    float* dinv = ws + 0;                   // 100000
    float* g    = ws + 100096;              // 32
    float* y1   = ws + 131072;              // 6,400,000
    float* acc1 = ws + 6531072;             // 6,400,000 (becomes h1)
    float* y2   = ws + 131072;              // 3,200,000 (reuse y1 region; y1 dead)
    float* acc2 = ws + 3331072;             // 3,200,000

    const int nb_n  = (N_NODES + 255) / 256;   // 391
    const int nb_e  = (N_EDGES + 255) / 256;   // 12500

    k_init<<<nb_n, 256, 0, stream>>>(dinv, g);
    k_count<<<nb_e, 256, 0, stream>>>(edst, dinv);
    k_rsqrt<<<nb_n, 256, 0, stream>>>(dinv);

    k_gemm1<<<nb_n, 256, 0, stream>>>(x, W1, dinv, y1, acc1);
    k_scatter1<<<(N_EDGES * 64) / 256, 256, 0, stream>>>(esrc, edst, y1, acc1);
    k_finish1<<<(N_NODES * H1 + 255) / 256, 256, 0, stream>>>(acc1, dinv, b1);

    k_gemm2<<<nb_n, 256, 0, stream>>>(acc1, W2, dinv, y2, acc2);
    k_scatter2<<<(N_EDGES * 32) / 256, 256, 0, stream>>>(esrc, edst, y2, acc2);
    k_finish2_pool<<<(N_NODES + 7) / 8, 256, 0, stream>>>(acc2, dinv, b2, g);

    k_fc<<<(C_OUT + 255) / 256, 256, 0, stream>>>(g, Wfc, bfc, out);
}

// Round 3
// 1251.315 us; speedup vs baseline: 1.3057x; 1.3057x over previous
//
#include <hip/hip_runtime.h>

#define N_NODES 100000
#define N_EDGES 3200000
#define F_IN 256
#define H1 64
#define H2 32
#define C_OUT 1000

// ---- workspace layout (4-byte units) ----
// g        : [0, 32)                  float
// row_ofs  : [64, 100065)             int   (N+1)
// csr_src  : [100096, 3300096)        int   (E)
// y1       : [3300096, 9700096)       float (N*64)   [cnt + cursor alias here pre-gemm1]
// y2       : [9700096, 12900096)      float (N*32)
// total 12,900,096 * 4 = 51.6 MB
#define OFF_G      0
#define OFF_ROW    64
#define OFF_CSR    100096
#define OFF_Y1     3300096
#define OFF_CNT    3300096      // aliases y1 (dead before gemm1)
#define OFF_CUR    3400128      // aliases y1 (dead before gemm1)
#define OFF_Y2     9700096

// ---------------- zero cnt + g ----------------
__global__ void k_zero(int* __restrict__ cnt, float* __restrict__ g) {
    int i = blockIdx.x * 256 + threadIdx.x;
    if (i < N_NODES) cnt[i] = 0;
    if (blockIdx.x == 0 && threadIdx.x < H2) g[threadIdx.x] = 0.0f;
}

// ---------------- histogram of dst ----------------
__global__ void k_hist(const int* __restrict__ dst, int* __restrict__ cnt) {
    int e = blockIdx.x * 256 + threadIdx.x;
    if (e < N_EDGES) atomicAdd(&cnt[dst[e]], 1);
}

// ---------------- single-block exclusive scan -> row_ofs, cursor ----------------
__global__ __launch_bounds__(1024) void k_scan(const int* __restrict__ cnt,
                                               int* __restrict__ row_ofs,
                                               int* __restrict__ cursor) {
    __shared__ int lds[1024];
    const int t = threadIdx.x;
    const int CH = (N_NODES + 1023) / 1024;  // 98
    int base = t * CH;
    int end = base + CH; if (end > N_NODES) end = N_NODES;
    int s = 0;
    for (int i = base; i < end; i++) s += cnt[i];
    lds[t] = s;
    __syncthreads();
    // Hillis-Steele inclusive scan
    for (int off = 1; off < 1024; off <<= 1) {
        int v = (t >= off) ? lds[t - off] : 0;
        __syncthreads();
        lds[t] += v;
        __syncthreads();
    }
    int run = lds[t] - s;  // exclusive prefix of this chunk
    for (int i = base; i < end; i++) {
        row_ofs[i] = run;
        cursor[i] = run;
        run += cnt[i];
    }
    if (t == 1023) row_ofs[N_NODES] = lds[1023];  // == E
}

// ---------------- CSR fill ----------------
__global__ void k_fill(const int* __restrict__ src, const int* __restrict__ dst,
                       int* __restrict__ cursor, int* __restrict__ csr_src) {
    int e = blockIdx.x * 256 + threadIdx.x;
    if (e < N_EDGES) {
        int d = dst[e];
        int pos = atomicAdd(&cursor[d], 1);
        csr_src[pos] = src[e];
    }
}

// ---------------- layer-1 GEMM: y1 = dinv * (x @ W1) ----------------
__global__ __launch_bounds__(256) void k_gemm1(const float* __restrict__ x,
                                               const float* __restrict__ W1,
                                               const int* __restrict__ row_ofs,
                                               float* __restrict__ y1) {
    __shared__ float w[F_IN][H1];  // 64 KB
    {
        const float4* Wv = (const float4*)W1;
        float4* wv = (float4*)&w[0][0];
        for (int i = threadIdx.x; i < F_IN * H1 / 4; i += 256) wv[i] = Wv[i];
    }
    __syncthreads();
    int n = blockIdx.x * 256 + threadIdx.x;
    if (n >= N_NODES) return;

    float acc[H1];
#pragma unroll
    for (int j = 0; j < H1; j++) acc[j] = 0.0f;

    const float4* xr = (const float4*)(x + (size_t)n * F_IN);
#pragma unroll 2
    for (int k0 = 0; k0 < F_IN / 4; k0++) {
        float4 xq = xr[k0];
#pragma unroll
        for (int d = 0; d < 4; d++) {
            float xv = (d == 0 ? xq.x : d == 1 ? xq.y : d == 2 ? xq.z : xq.w);
            const float4* wr = (const float4*)&w[k0 * 4 + d][0];
#pragma unroll
            for (int j4 = 0; j4 < H1 / 4; j4++) {
                float4 wq = wr[j4];
                acc[j4 * 4 + 0] += xv * wq.x;
                acc[j4 * 4 + 1] += xv * wq.y;
                acc[j4 * 4 + 2] += xv * wq.z;
                acc[j4 * 4 + 3] += xv * wq.w;
            }
        }
    }
    int r0 = row_ofs[n], r1 = row_ofs[n + 1];
    float dv = rsqrtf(1.0f + (float)(r1 - r0));
    float4* y1r = (float4*)(y1 + (size_t)n * H1);
#pragma unroll
    for (int j4 = 0; j4 < H1 / 4; j4++) {
        float4 o;
        o.x = acc[j4 * 4 + 0] * dv;
        o.y = acc[j4 * 4 + 1] * dv;
        o.z = acc[j4 * 4 + 2] * dv;
        o.w = acc[j4 * 4 + 3] * dv;
        y1r[j4] = o;
    }
}

// ---------------- fused: gather-agg layer1 + ReLU + GEMM2 -> y2 ----------------
// block = 256 threads = 4 waves = 4 nodes. h1 lives only in LDS.
__global__ __launch_bounds__(256) void k_agg1_gemm2(const float* __restrict__ y1,
                                                    const int* __restrict__ row_ofs,
                                                    const int* __restrict__ csr_src,
                                                    const float* __restrict__ b1,
                                                    const float* __restrict__ W2,
                                                    float* __restrict__ y2) {
    __shared__ float w2s[H1][H2];  // 8 KB
    __shared__ float hbuf[4][H1];  // 1 KB
    {
        const float4* Wv = (const float4*)W2;
        float4* wv = (float4*)&w2s[0][0];
        for (int i = threadIdx.x; i < H1 * H2 / 4; i += 256) wv[i] = Wv[i];
    }

    const int t = threadIdx.x;
    const int wid = t >> 6;        // wave id 0..3
    const int c = t & 63;          // channel
    const int n = blockIdx.x * 4 + wid;

    int r0 = row_ofs[n], r1 = row_ofs[n + 1];
    float dv = rsqrtf(1.0f + (float)(r1 - r0));

    float a0 = y1[(size_t)n * H1 + c];  // self-loop
    float a1 = 0.0f;
    int p = r0;
    for (; p + 1 < r1; p += 2) {
        int s0 = csr_src[p];
        int s1 = csr_src[p + 1];
        a0 += y1[(size_t)s0 * H1 + c];
        a1 += y1[(size_t)s1 * H1 + c];
    }
    if (p < r1) {
        int s0 = csr_src[p];
        a0 += y1[(size_t)s0 * H1 + c];
    }
    float hv = dv * (a0 + a1) + b1[c];
    hbuf[wid][c] = hv > 0.0f ? hv : 0.0f;
    __syncthreads();

    // GEMM2: 128 threads compute 4 nodes x 32 outputs
    if (t < 128) {
        int w = t >> 5, j = t & 31;
        int n2 = blockIdx.x * 4 + w;
        float dot = 0.0f;
#pragma unroll
        for (int cc = 0; cc < H1; cc++) dot += hbuf[w][cc] * w2s[cc][j];
        int q0 = row_ofs[n2], q1 = row_ofs[n2 + 1];
        float dv2 = rsqrtf(1.0f + (float)(q1 - q0));
        y2[(size_t)n2 * H2 + j] = dv2 * dot;
    }
}

// ---------------- gather-agg layer2 + ReLU + mean-pool partials ----------------
// block = 256 = 8 half-waves = 8 nodes
__global__ __launch_bounds__(256) void k_agg2_pool(const float* __restrict__ y2,
                                                   const int* __restrict__ row_ofs,
                                                   const int* __restrict__ csr_src,
                                                   const float* __restrict__ b2,
                                                   float* __restrict__ g) {
    __shared__ float red[256];
    const int t = threadIdx.x;
    const int n = blockIdx.x * 8 + (t >> 5);
    const int c = t & 31;

    int r0 = row_ofs[n], r1 = row_ofs[n + 1];
    float dv = rsqrtf(1.0f + (float)(r1 - r0));

    float a0 = y2[(size_t)n * H2 + c];  // self-loop
    float a1 = 0.0f;
    int p = r0;
    for (; p + 1 < r1; p += 2) {
        int s0 = csr_src[p];
        int s1 = csr_src[p + 1];
        a0 += y2[(size_t)s0 * H2 + c];
        a1 += y2[(size_t)s1 * H2 + c];
    }
    if (p < r1) {
        int s0 = csr_src[p];
        a0 += y2[(size_t)s0 * H2 + c];
    }
    float hv = dv * (a0 + a1) + b2[c];
    red[t] = hv > 0.0f ? hv : 0.0f;
    __syncthreads();
    if (t < 128) red[t] += red[t + 128];
    __syncthreads();
    if (t < 64) red[t] += red[t + 64];
    __syncthreads();
    if (t < 32) {
        float s = red[t] + red[t + 32];
        atomicAdd(&g[t], s);
    }
}

__global__ void k_fc(const float* __restrict__ g, const float* __restrict__ Wfc,
                     const float* __restrict__ bfc, float* __restrict__ out) {
    int c = blockIdx.x * 256 + threadIdx.x;
    if (c < C_OUT) {
        const float invn = 1.0f / (float)N_NODES;
        float s = bfc[c];
#pragma unroll
        for (int k = 0; k < H2; k++) s += (g[k] * invn) * Wfc[k * C_OUT + c];
        out[c] = s;
    }
}

extern "C" void kernel_launch(void* const* d_in, const int* in_sizes, int n_in,
                              void* d_out, int out_size, void* d_ws, size_t ws_size,
                              hipStream_t stream) {
    const float* x   = (const float*)d_in[0];
    const int* esrc  = (const int*)d_in[1];
    const int* edst  = (const int*)d_in[2];
    const float* W1  = (const float*)d_in[3];
    const float* b1  = (const float*)d_in[4];
    const float* W2  = (const float*)d_in[5];
    const float* b2  = (const float*)d_in[6];
    const float* Wfc = (const float*)d_in[7];
    const float* bfc = (const float*)d_in[8];
    float* out = (float*)d_out;

    float* ws = (float*)d_ws;
    float* g       = ws + OFF_G;
    int*   row_ofs = (int*)(ws + OFF_ROW);
    int*   csr_src = (int*)(ws + OFF_CSR);
    float* y1      = ws + OFF_Y1;
    int*   cnt     = (int*)(ws + OFF_CNT);
    int*   cursor  = (int*)(ws + OFF_CUR);
    float* y2      = ws + OFF_Y2;

    const int nb_n = (N_NODES + 255) / 256;  // 391
    const int nb_e = (N_EDGES + 255) / 256;  // 12500

    k_zero<<<nb_n, 256, 0, stream>>>(cnt, g);
    k_hist<<<nb_e, 256, 0, stream>>>(edst, cnt);
    k_scan<<<1, 1024, 0, stream>>>(cnt, row_ofs, cursor);
    k_fill<<<nb_e, 256, 0, stream>>>(esrc, edst, cursor, csr_src);

    k_gemm1<<<nb_n, 256, 0, stream>>>(x, W1, row_ofs, y1);
    k_agg1_gemm2<<<N_NODES / 4, 256, 0, stream>>>(y1, row_ofs, csr_src, b1, W2, y2);
    k_agg2_pool<<<N_NODES / 8, 256, 0, stream>>>(y2, row_ofs, csr_src, b2, g);

    k_fc<<<(C_OUT + 255) / 256, 256, 0, stream>>>(g, Wfc, bfc, out);
}

// Round 4
// 867.443 us; speedup vs baseline: 1.8836x; 1.4425x over previous
//
#include <hip/hip_runtime.h>

#define N_NODES 100000
#define N_EDGES 3200000
#define F_IN 256
#define H1 64
#define H2 32
#define C_OUT 1000

// ---- workspace layout (4-byte units) ----
#define OFF_G      0          // float[32]
#define OFF_DINV   64         // float[N]
#define OFF_HEAD   100096     // int[N]
#define OFF_NEXT   200128     // int[E]
#define OFF_Y1     3400192    // float[N*64]
#define OFF_Y2     9800192    // float[N*32]
// total 13,000,192 * 4B = 52.0 MB

// ---------------- init: head=-1, g=0 ----------------
__global__ void k_init(int* __restrict__ head, float* __restrict__ g) {
    int i = blockIdx.x * 256 + threadIdx.x;
    if (i < N_NODES) head[i] = -1;
    if (blockIdx.x == 0 && threadIdx.x < H2) g[threadIdx.x] = 0.0f;
}

// ---------------- linked-list build: coalesced next[] write ----------------
__global__ void k_build(const int* __restrict__ dst, int* __restrict__ head,
                        int* __restrict__ next) {
    int e = blockIdx.x * 256 + threadIdx.x;
    if (e < N_EDGES) {
        int d = dst[e];
        int prev = atomicExch(&head[d], e);
        next[e] = prev;
    }
}

// ---------------- degree via chain walk (latency-bound, ~1 round) ----------------
__global__ void k_deg(const int* __restrict__ head, const int* __restrict__ next,
                      float* __restrict__ dinv) {
    int n = blockIdx.x * 256 + threadIdx.x;
    if (n < N_NODES) {
        int cdeg = 0;
        int e = head[n];
        while (e >= 0) { cdeg++; e = next[e]; }
        dinv[n] = rsqrtf(1.0f + (float)cdeg);
    }
}

// ---------------- layer-1 GEMM, 2-node register blocking ----------------
// block=256 threads covers 512 nodes; each W element read from LDS feeds 2 nodes.
__global__ __launch_bounds__(256) void k_gemm1(const float* __restrict__ x,
                                               const float* __restrict__ W1,
                                               const float* __restrict__ dinv,
                                               float* __restrict__ y1) {
    __shared__ float w[F_IN][H1];  // 64 KB
    {
        const float4* Wv = (const float4*)W1;
        float4* wv = (float4*)&w[0][0];
        for (int i = threadIdx.x; i < F_IN * H1 / 4; i += 256) wv[i] = Wv[i];
    }
    __syncthreads();
    int n0 = blockIdx.x * 512 + threadIdx.x;
    int n1 = n0 + 256;
    bool v0 = n0 < N_NODES, v1 = n1 < N_NODES;
    int n0c = v0 ? n0 : 0, n1c = v1 ? n1 : 0;

    float acc0[H1], acc1[H1];
#pragma unroll
    for (int j = 0; j < H1; j++) { acc0[j] = 0.0f; acc1[j] = 0.0f; }

    const float4* xr0 = (const float4*)(x + (size_t)n0c * F_IN);
    const float4* xr1 = (const float4*)(x + (size_t)n1c * F_IN);
#pragma unroll 2
    for (int k0 = 0; k0 < F_IN / 4; k0++) {
        float4 xa = xr0[k0];
        float4 xb = xr1[k0];
#pragma unroll
        for (int d = 0; d < 4; d++) {
            float xv0 = (d == 0 ? xa.x : d == 1 ? xa.y : d == 2 ? xa.z : xa.w);
            float xv1 = (d == 0 ? xb.x : d == 1 ? xb.y : d == 2 ? xb.z : xb.w);
            const float4* wr = (const float4*)&w[k0 * 4 + d][0];
#pragma unroll
            for (int j4 = 0; j4 < H1 / 4; j4++) {
                float4 wq = wr[j4];
                acc0[j4 * 4 + 0] += xv0 * wq.x;
                acc0[j4 * 4 + 1] += xv0 * wq.y;
                acc0[j4 * 4 + 2] += xv0 * wq.z;
                acc0[j4 * 4 + 3] += xv0 * wq.w;
                acc1[j4 * 4 + 0] += xv1 * wq.x;
                acc1[j4 * 4 + 1] += xv1 * wq.y;
                acc1[j4 * 4 + 2] += xv1 * wq.z;
                acc1[j4 * 4 + 3] += xv1 * wq.w;
            }
        }
    }
    if (v0) {
        float dv = dinv[n0];
        float4* o = (float4*)(y1 + (size_t)n0 * H1);
#pragma unroll
        for (int j4 = 0; j4 < H1 / 4; j4++) {
            float4 q;
            q.x = acc0[j4 * 4 + 0] * dv; q.y = acc0[j4 * 4 + 1] * dv;
            q.z = acc0[j4 * 4 + 2] * dv; q.w = acc0[j4 * 4 + 3] * dv;
            o[j4] = q;
        }
    }
    if (v1) {
        float dv = dinv[n1];
        float4* o = (float4*)(y1 + (size_t)n1 * H1);
#pragma unroll
        for (int j4 = 0; j4 < H1 / 4; j4++) {
            float4 q;
            q.x = acc1[j4 * 4 + 0] * dv; q.y = acc1[j4 * 4 + 1] * dv;
            q.z = acc1[j4 * 4 + 2] * dv; q.w = acc1[j4 * 4 + 3] * dv;
            o[j4] = q;
        }
    }
}

// ---------------- fused: chain-gather layer1 + ReLU + GEMM2 -> y2 ----------------
// block=256 = 4 waves; each wave walks TWO chains (2-way ILP on the pointer chase).
// 8 nodes per block; gemm2 uses all 256 threads (8 nodes x 32 cols).
__global__ __launch_bounds__(256) void k_agg1_gemm2(const float* __restrict__ y1,
                                                    const int* __restrict__ head,
                                                    const int* __restrict__ next,
                                                    const int* __restrict__ src,
                                                    const float* __restrict__ dinv,
                                                    const float* __restrict__ b1,
                                                    const float* __restrict__ W2,
                                                    float* __restrict__ y2) {
    __shared__ float w2s[H1][H2];  // 8 KB
    __shared__ float hbuf[8][H1];  // 2 KB
    {
        const float4* Wv = (const float4*)W2;
        float4* wv = (float4*)&w2s[0][0];
        for (int i = threadIdx.x; i < H1 * H2 / 4; i += 256) wv[i] = Wv[i];
    }

    const int t = threadIdx.x;
    const int wid = t >> 6;
    const int c = t & 63;
    const int n0 = blockIdx.x * 8 + wid * 2;
    const int n1 = n0 + 1;

    float a0 = y1[(size_t)n0 * H1 + c];  // self-loop
    float a1 = y1[(size_t)n1 * H1 + c];
    int e0 = head[n0], e1 = head[n1];
    while (e0 >= 0 && e1 >= 0) {
        int s0 = src[e0], s1 = src[e1];
        int t0 = next[e0], t1 = next[e1];
        a0 += y1[(size_t)s0 * H1 + c];
        a1 += y1[(size_t)s1 * H1 + c];
        e0 = t0; e1 = t1;
    }
    while (e0 >= 0) {
        int s0 = src[e0]; int t0 = next[e0];
        a0 += y1[(size_t)s0 * H1 + c]; e0 = t0;
    }
    while (e1 >= 0) {
        int s1 = src[e1]; int t1 = next[e1];
        a1 += y1[(size_t)s1 * H1 + c]; e1 = t1;
    }
    float h0 = dinv[n0] * a0 + b1[c];
    float h1v = dinv[n1] * a1 + b1[c];
    hbuf[wid * 2 + 0][c] = h0 > 0.0f ? h0 : 0.0f;
    hbuf[wid * 2 + 1][c] = h1v > 0.0f ? h1v : 0.0f;
    __syncthreads();

    // GEMM2: 256 threads = 8 nodes x 32 outputs
    {
        int w = t >> 5, j = t & 31;
        int n2 = blockIdx.x * 8 + w;
        float dot = 0.0f;
#pragma unroll
        for (int cc = 0; cc < H1; cc++) dot += hbuf[w][cc] * w2s[cc][j];
        y2[(size_t)n2 * H2 + j] = dinv[n2] * dot;
    }
}

// ---------------- chain-gather layer2 + ReLU + mean-pool partials ----------------
// block=256 = 8 half-waves = 8 nodes (2 independent chains per wave).
__global__ __launch_bounds__(256) void k_agg2_pool(const float* __restrict__ y2,
                                                   const int* __restrict__ head,
                                                   const int* __restrict__ next,
                                                   const int* __restrict__ src,
                                                   const float* __restrict__ dinv,
                                                   const float* __restrict__ b2,
                                                   float* __restrict__ g) {
    __shared__ float red[256];
    const int t = threadIdx.x;
    const int n = blockIdx.x * 8 + (t >> 5);
    const int c = t & 31;

    float a = y2[(size_t)n * H2 + c];  // self-loop
    int e = head[n];
    while (e >= 0) {
        int s = src[e]; int nx = next[e];
        a += y2[(size_t)s * H2 + c]; e = nx;
    }
    float hv = dinv[n] * a + b2[c];
    red[t] = hv > 0.0f ? hv : 0.0f;
    __syncthreads();
    if (t < 128) red[t] += red[t + 128];
    __syncthreads();
    if (t < 64) red[t] += red[t + 64];
    __syncthreads();
    if (t < 32) {
        float s = red[t] + red[t + 32];
        atomicAdd(&g[t], s);
    }
}

__global__ void k_fc(const float* __restrict__ g, const float* __restrict__ Wfc,
                     const float* __restrict__ bfc, float* __restrict__ out) {
    int c = blockIdx.x * 256 + threadIdx.x;
    if (c < C_OUT) {
        const float invn = 1.0f / (float)N_NODES;
        float s = bfc[c];
#pragma unroll
        for (int k = 0; k < H2; k++) s += (g[k] * invn) * Wfc[k * C_OUT + c];
        out[c] = s;
    }
}

extern "C" void kernel_launch(void* const* d_in, const int* in_sizes, int n_in,
                              void* d_out, int out_size, void* d_ws, size_t ws_size,
                              hipStream_t stream) {
    const float* x   = (const float*)d_in[0];
    const int* esrc  = (const int*)d_in[1];
    const int* edst  = (const int*)d_in[2];
    const float* W1  = (const float*)d_in[3];
    const float* b1  = (const float*)d_in[4];
    const float* W2  = (const float*)d_in[5];
    const float* b2  = (const float*)d_in[6];
    const float* Wfc = (const float*)d_in[7];
    const float* bfc = (const float*)d_in[8];
    float* out = (float*)d_out;

    float* ws = (float*)d_ws;
    float* g    = ws + OFF_G;
    float* dinv = ws + OFF_DINV;
    int*   head = (int*)(ws + OFF_HEAD);
    int*   next = (int*)(ws + OFF_NEXT);
    float* y1   = ws + OFF_Y1;
    float* y2   = ws + OFF_Y2;

    const int nb_n = (N_NODES + 255) / 256;  // 391
    const int nb_e = (N_EDGES + 255) / 256;  // 12500

    k_init<<<nb_n, 256, 0, stream>>>(head, g);
    k_build<<<nb_e, 256, 0, stream>>>(edst, head, next);
    k_deg<<<nb_n, 256, 0, stream>>>(head, next, dinv);

    k_gemm1<<<(N_NODES + 511) / 512, 256, 0, stream>>>(x, W1, dinv, y1);
    k_agg1_gemm2<<<N_NODES / 8, 256, 0, stream>>>(y1, head, next, esrc, dinv, b1, W2, y2);
    k_agg2_pool<<<N_NODES / 8, 256, 0, stream>>>(y2, head, next, esrc, dinv, b2, g);

    k_fc<<<(C_OUT + 255) / 256, 256, 0, stream>>>(g, Wfc, bfc, out);
}

// Round 5
// 856.168 us; speedup vs baseline: 1.9084x; 1.0132x over previous
//
#include <hip/hip_runtime.h>

#define N_NODES 100000
#define N_EDGES 3200000
#define F_IN 256
#define H1 64
#define H2 32
#define C_OUT 1000

// ---- workspace layout (4-byte units) ----
#define OFF_G      0          // float[32]
#define OFF_DINV   64         // float[N]
#define OFF_HEAD   100096     // int[N]
#define OFF_NEXT   200128     // int[E]
#define OFF_Y1B    3400192    // ushort[N*64] = 3,200,000 floats
#define OFF_Y2B    6600192    // ushort[N*32] = 1,600,000 floats
// total 8,200,192 * 4B = 32.8 MB

__device__ __forceinline__ unsigned short f2bf(float f) {
    unsigned u = __float_as_uint(f);
    u += 0x7FFFu + ((u >> 16) & 1u);  // round-to-nearest-even
    return (unsigned short)(u >> 16);
}
__device__ __forceinline__ float bf2f(unsigned short s) {
    return __uint_as_float(((unsigned)s) << 16);
}

// ---------------- init: head=-1, g=0 ----------------
__global__ void k_init(int* __restrict__ head, float* __restrict__ g) {
    int i = blockIdx.x * 256 + threadIdx.x;
    if (i < N_NODES) head[i] = -1;
    if (blockIdx.x == 0 && threadIdx.x < H2) g[threadIdx.x] = 0.0f;
}

// ---------------- linked-list build: coalesced next[] write ----------------
__global__ void k_build(const int* __restrict__ dst, int* __restrict__ head,
                        int* __restrict__ next) {
    int e = blockIdx.x * 256 + threadIdx.x;
    if (e < N_EDGES) {
        int d = dst[e];
        int prev = atomicExch(&head[d], e);
        next[e] = prev;
    }
}

// ---------------- degree via chain walk ----------------
__global__ void k_deg(const int* __restrict__ head, const int* __restrict__ next,
                      float* __restrict__ dinv) {
    int n = blockIdx.x * 256 + threadIdx.x;
    if (n < N_NODES) {
        int cdeg = 0;
        int e = head[n];
        while (e >= 0) { cdeg++; e = next[e]; }
        dinv[n] = rsqrtf(1.0f + (float)cdeg);
    }
}

// ---------------- layer-1 GEMM, 2-node register blocking, bf16 output ----------------
__global__ __launch_bounds__(256) void k_gemm1(const float* __restrict__ x,
                                               const float* __restrict__ W1,
                                               const float* __restrict__ dinv,
                                               unsigned short* __restrict__ y1b) {
    __shared__ float w[F_IN][H1];  // 64 KB
    {
        const float4* Wv = (const float4*)W1;
        float4* wv = (float4*)&w[0][0];
        for (int i = threadIdx.x; i < F_IN * H1 / 4; i += 256) wv[i] = Wv[i];
    }
    __syncthreads();
    int n0 = blockIdx.x * 512 + threadIdx.x;
    int n1 = n0 + 256;
    bool v0 = n0 < N_NODES, v1 = n1 < N_NODES;
    int n0c = v0 ? n0 : 0, n1c = v1 ? n1 : 0;

    float acc0[H1], acc1[H1];
#pragma unroll
    for (int j = 0; j < H1; j++) { acc0[j] = 0.0f; acc1[j] = 0.0f; }

    const float4* xr0 = (const float4*)(x + (size_t)n0c * F_IN);
    const float4* xr1 = (const float4*)(x + (size_t)n1c * F_IN);
#pragma unroll 2
    for (int k0 = 0; k0 < F_IN / 4; k0++) {
        float4 xa = xr0[k0];
        float4 xb = xr1[k0];
#pragma unroll
        for (int d = 0; d < 4; d++) {
            float xv0 = (d == 0 ? xa.x : d == 1 ? xa.y : d == 2 ? xa.z : xa.w);
            float xv1 = (d == 0 ? xb.x : d == 1 ? xb.y : d == 2 ? xb.z : xb.w);
            const float4* wr = (const float4*)&w[k0 * 4 + d][0];
#pragma unroll
            for (int j4 = 0; j4 < H1 / 4; j4++) {
                float4 wq = wr[j4];
                acc0[j4 * 4 + 0] += xv0 * wq.x;
                acc0[j4 * 4 + 1] += xv0 * wq.y;
                acc0[j4 * 4 + 2] += xv0 * wq.z;
                acc0[j4 * 4 + 3] += xv0 * wq.w;
                acc1[j4 * 4 + 0] += xv1 * wq.x;
                acc1[j4 * 4 + 1] += xv1 * wq.y;
                acc1[j4 * 4 + 2] += xv1 * wq.z;
                acc1[j4 * 4 + 3] += xv1 * wq.w;
            }
        }
    }
    if (v0) {
        float dv = dinv[n0];
        unsigned pk[H1 / 2];
#pragma unroll
        for (int j2 = 0; j2 < H1 / 2; j2++) {
            unsigned lo = f2bf(acc0[2 * j2] * dv);
            unsigned hi = f2bf(acc0[2 * j2 + 1] * dv);
            pk[j2] = lo | (hi << 16);
        }
        uint4* o = (uint4*)(y1b + (size_t)n0 * H1);
#pragma unroll
        for (int q = 0; q < H1 / 8; q++)
            o[q] = make_uint4(pk[q * 4], pk[q * 4 + 1], pk[q * 4 + 2], pk[q * 4 + 3]);
    }
    if (v1) {
        float dv = dinv[n1];
        unsigned pk[H1 / 2];
#pragma unroll
        for (int j2 = 0; j2 < H1 / 2; j2++) {
            unsigned lo = f2bf(acc1[2 * j2] * dv);
            unsigned hi = f2bf(acc1[2 * j2 + 1] * dv);
            pk[j2] = lo | (hi << 16);
        }
        uint4* o = (uint4*)(y1b + (size_t)n1 * H1);
#pragma unroll
        for (int q = 0; q < H1 / 8; q++)
            o[q] = make_uint4(pk[q * 4], pk[q * 4 + 1], pk[q * 4 + 2], pk[q * 4 + 3]);
    }
}

// ---------------- fused: chain-gather layer1 + ReLU + GEMM2 -> y2 (bf16) ----------------
// block=256 = 4 waves; each wave walks TWO chains. 8 nodes/block.
__global__ __launch_bounds__(256) void k_agg1_gemm2(const unsigned short* __restrict__ y1b,
                                                    const int* __restrict__ head,
                                                    const int* __restrict__ next,
                                                    const int* __restrict__ src,
                                                    const float* __restrict__ dinv,
                                                    const float* __restrict__ b1,
                                                    const float* __restrict__ W2,
                                                    unsigned short* __restrict__ y2b) {
    __shared__ float w2s[H1][H2];  // 8 KB
    __shared__ float hbuf[8][H1];  // 2 KB
    {
        const float4* Wv = (const float4*)W2;
        float4* wv = (float4*)&w2s[0][0];
        for (int i = threadIdx.x; i < H1 * H2 / 4; i += 256) wv[i] = Wv[i];
    }

    const int t = threadIdx.x;
    const int wid = t >> 6;
    const int c = t & 63;
    const int n0 = blockIdx.x * 8 + wid * 2;
    const int n1 = n0 + 1;

    float a0 = bf2f(y1b[(size_t)n0 * H1 + c]);  // self-loop
    float a1 = bf2f(y1b[(size_t)n1 * H1 + c]);
    int e0 = head[n0], e1 = head[n1];
    while (e0 >= 0 && e1 >= 0) {
        int s0 = src[e0], s1 = src[e1];
        int t0 = next[e0], t1 = next[e1];
        a0 += bf2f(y1b[(size_t)s0 * H1 + c]);
        a1 += bf2f(y1b[(size_t)s1 * H1 + c]);
        e0 = t0; e1 = t1;
    }
    while (e0 >= 0) {
        int s0 = src[e0]; int t0 = next[e0];
        a0 += bf2f(y1b[(size_t)s0 * H1 + c]); e0 = t0;
    }
    while (e1 >= 0) {
        int s1 = src[e1]; int t1 = next[e1];
        a1 += bf2f(y1b[(size_t)s1 * H1 + c]); e1 = t1;
    }
    float h0 = dinv[n0] * a0 + b1[c];
    float h1v = dinv[n1] * a1 + b1[c];
    hbuf[wid * 2 + 0][c] = h0 > 0.0f ? h0 : 0.0f;
    hbuf[wid * 2 + 1][c] = h1v > 0.0f ? h1v : 0.0f;
    __syncthreads();

    // GEMM2: 256 threads = 8 nodes x 32 outputs
    {
        int w = t >> 5, j = t & 31;
        int n2 = blockIdx.x * 8 + w;
        float dot = 0.0f;
#pragma unroll
        for (int cc = 0; cc < H1; cc++) dot += hbuf[w][cc] * w2s[cc][j];
        y2b[(size_t)n2 * H2 + j] = f2bf(dinv[n2] * dot);
    }
}

// ---------------- chain-gather layer2 + ReLU + mean-pool partials ----------------
// block=256 = 8 half-waves = 8 nodes
__global__ __launch_bounds__(256) void k_agg2_pool(const unsigned short* __restrict__ y2b,
                                                   const int* __restrict__ head,
                                                   const int* __restrict__ next,
                                                   const int* __restrict__ src,
                                                   const float* __restrict__ dinv,
                                                   const float* __restrict__ b2,
                                                   float* __restrict__ g) {
    __shared__ float red[256];
    const int t = threadIdx.x;
    const int n = blockIdx.x * 8 + (t >> 5);
    const int c = t & 31;

    float a = bf2f(y2b[(size_t)n * H2 + c]);  // self-loop
    int e = head[n];
    while (e >= 0) {
        int s = src[e]; int nx = next[e];
        a += bf2f(y2b[(size_t)s * H2 + c]); e = nx;
    }
    float hv = dinv[n] * a + b2[c];
    red[t] = hv > 0.0f ? hv : 0.0f;
    __syncthreads();
    if (t < 128) red[t] += red[t + 128];
    __syncthreads();
    if (t < 64) red[t] += red[t + 64];
    __syncthreads();
    if (t < 32) {
        float s = red[t] + red[t + 32];
        atomicAdd(&g[t], s);
    }
}

__global__ void k_fc(const float* __restrict__ g, const float* __restrict__ Wfc,
                     const float* __restrict__ bfc, float* __restrict__ out) {
    int c = blockIdx.x * 256 + threadIdx.x;
    if (c < C_OUT) {
        const float invn = 1.0f / (float)N_NODES;
        float s = bfc[c];
#pragma unroll
        for (int k = 0; k < H2; k++) s += (g[k] * invn) * Wfc[k * C_OUT + c];
        out[c] = s;
    }
}

extern "C" void kernel_launch(void* const* d_in, const int* in_sizes, int n_in,
                              void* d_out, int out_size, void* d_ws, size_t ws_size,
                              hipStream_t stream) {
    const float* x   = (const float*)d_in[0];
    const int* esrc  = (const int*)d_in[1];
    const int* edst  = (const int*)d_in[2];
    const float* W1  = (const float*)d_in[3];
    const float* b1  = (const float*)d_in[4];
    const float* W2  = (const float*)d_in[5];
    const float* b2  = (const float*)d_in[6];
    const float* Wfc = (const float*)d_in[7];
    const float* bfc = (const float*)d_in[8];
    float* out = (float*)d_out;

    float* ws = (float*)d_ws;
    float* g    = ws + OFF_G;
    float* dinv = ws + OFF_DINV;
    int*   head = (int*)(ws + OFF_HEAD);
    int*   next = (int*)(ws + OFF_NEXT);
    unsigned short* y1b = (unsigned short*)(ws + OFF_Y1B);
    unsigned short* y2b = (unsigned short*)(ws + OFF_Y2B);

    const int nb_n = (N_NODES + 255) / 256;  // 391
    const int nb_e = (N_EDGES + 255) / 256;  // 12500

    k_init<<<nb_n, 256, 0, stream>>>(head, g);
    k_build<<<nb_e, 256, 0, stream>>>(edst, head, next);
    k_deg<<<nb_n, 256, 0, stream>>>(head, next, dinv);

    k_gemm1<<<(N_NODES + 511) / 512, 256, 0, stream>>>(x, W1, dinv, y1b);
    k_agg1_gemm2<<<N_NODES / 8, 256, 0, stream>>>(y1b, head, next, esrc, dinv, b1, W2, y2b);
    k_agg2_pool<<<N_NODES / 8, 256, 0, stream>>>(y2b, head, next, esrc, dinv, b2, g);

    k_fc<<<(C_OUT + 255) / 256, 256, 0, stream>>>(g, Wfc, bfc, out);
}